// Round 3
// baseline (617.332 us; speedup 1.0000x reference)
//
#include <hip/hip_runtime.h>

#define BATCH 512
#define NC 3
#define TT 4096
#define HH 17

// tanh(x) = 1 - 2/(2^(2x*log2e)+1); exact saturation at +/-1, ~1e-7 abs error
__device__ __forceinline__ float fast_tanh(float x) {
    float e = exp2f(x * 2.8853900817779268f);  // 2*log2(e)
    float r = __builtin_amdgcn_rcpf(e + 1.0f);
    return fmaf(-2.0f, r, 1.0f);
}

// Full-wave sum of per-half partials: after swapping p with a copy of itself,
// a = upper-half partial in ALL lanes, b = lower-half partial in ALL lanes.
__device__ __forceinline__ float half_sum(float p) {
    float a = p;
    float b;
    asm volatile("v_mov_b32 %1, %0\n\t"
                 "v_permlane32_swap_b32 %0, %1"
                 : "+v"(a), "=&v"(b));
    return a + b;
}

__device__ __forceinline__ float bperm(int idx, float v) {
    return __int_as_float(__builtin_amdgcn_ds_bpermute(idx, __float_as_int(v)));
}

template <int DIR>
__device__ float run_rnn(const float4* __restrict__ x0,
                         const float4* __restrict__ x1,
                         const float4* __restrict__ x2,
                         const float* __restrict__ W_ih,
                         const float* __restrict__ W_hh,
                         const float* __restrict__ b_ih,
                         const float* __restrict__ b_hh,
                         int row, int half) {
    // Split the 17-term dot: lower half lanes own terms j=0..8 (+proj+bias),
    // upper half lanes own terms j=9..16 (9th term padded with w=0).
    float w[9];
    float wx0, wx1, wx2, bias;
    if (half == 0) {
#pragma unroll
        for (int k = 0; k < 9; ++k) w[k] = W_hh[row * HH + k];
        wx0 = W_ih[row * NC + 0];
        wx1 = W_ih[row * NC + 1];
        wx2 = W_ih[row * NC + 2];
        bias = b_ih[row] + b_hh[row];
    } else {
#pragma unroll
        for (int k = 0; k < 8; ++k) w[k] = W_hh[row * HH + 9 + k];
        w[8] = 0.0f;
        wx0 = wx1 = wx2 = 0.0f;
        bias = 0.0f;
    }

    // bpermute byte-indices for the h refresh: lane pulls h[j] from lane j
    // (lanes 0..16 hold rows 0..16); lower half needs j=k, upper j=9+k.
    int idx[9];
#pragma unroll
    for (int k = 0; k < 9; ++k) {
        int j = half ? (9 + k) : k;
        if (j > HH - 1) j = HH - 1;  // padded term, value irrelevant (w=0)
        idx[k] = j << 2;
    }

    float h[9];
#pragma unroll
    for (int k = 0; k < 9; ++k) h[k] = 0.0f;
    float hsum = 0.0f;

    const int NB = TT / 4;
    int t4 = DIR ? NB - 1 : 0;
    float4 ca = x0[t4], cbv = x1[t4], ccv = x2[t4];

    for (int blk = 0; blk < NB; ++blk) {
        int nxt = (blk + 1 < NB) ? blk + 1 : blk;  // clamped prefetch
        int t4n = DIR ? NB - 1 - nxt : nxt;
        float4 na = x0[t4n], nbv = x1[t4n], ncv = x2[t4n];

        float xa[4] = {ca.x, ca.y, ca.z, ca.w};
        float xb[4] = {cbv.x, cbv.y, cbv.z, cbv.w};
        float xc[4] = {ccv.x, ccv.y, ccv.z, ccv.w};

#pragma unroll
        for (int k = 0; k < 4; ++k) {
            const int kk = DIR ? (3 - k) : k;  // compile-time constant index
            // proj is h-independent: schedules ahead of the chain
            float p = fmaf(wx0, xa[kk], bias);
            p = fmaf(wx1, xb[kk], p);
            p = fmaf(wx2, xc[kk], p);
            // 9-term half-dot, 3 accumulator chains
            float d1 = 0.0f, d2 = 0.0f;
            p  = fmaf(w[0], h[0], p);
            d1 = fmaf(w[1], h[1], d1);
            d2 = fmaf(w[2], h[2], d2);
            p  = fmaf(w[3], h[3], p);
            d1 = fmaf(w[4], h[4], d1);
            d2 = fmaf(w[5], h[5], d2);
            p  = fmaf(w[6], h[6], p);
            d1 = fmaf(w[7], h[7], d1);
            d2 = fmaf(w[8], h[8], d2);
            float s = half_sum(p + (d1 + d2));  // full 17-dot + bias, all lanes
            float hn = fast_tanh(s);
            hsum += hn;
            // refresh this lane's 9 h values via bpermute (rows live in lanes 0..16)
#pragma unroll
            for (int j = 0; j < 9; ++j) h[j] = bperm(idx[j], hn);
        }
        ca = na; cbv = nbv; ccv = ncv;
    }
    return hsum;
}

__global__ __launch_bounds__(64) void rnn_kernel(
    const float* __restrict__ x,
    const float* __restrict__ W_ih_f, const float* __restrict__ W_hh_f,
    const float* __restrict__ b_ih_f, const float* __restrict__ b_hh_f,
    const float* __restrict__ W_ih_b, const float* __restrict__ W_hh_b,
    const float* __restrict__ b_ih_b, const float* __restrict__ b_hh_b,
    float* __restrict__ partial) {
    int wid = blockIdx.x;       // 0..1023  (batch, dir)
    int b = wid >> 1;
    int dir = wid & 1;
    int lane = threadIdx.x;     // 0..63
    int half = lane >> 5;
    int r0 = lane & 31;
    int row = r0 < HH ? r0 : HH - 1;  // clamp dead lanes (no OOB, dup work)

    const float* xb = x + (size_t)b * NC * TT;
    const float4* x0 = reinterpret_cast<const float4*>(xb);
    const float4* x1 = reinterpret_cast<const float4*>(xb + TT);
    const float4* x2 = reinterpret_cast<const float4*>(xb + 2 * TT);

    float hsum;
    if (dir == 0)
        hsum = run_rnn<0>(x0, x1, x2, W_ih_f, W_hh_f, b_ih_f, b_hh_f, row, half);
    else
        hsum = run_rnn<1>(x0, x1, x2, W_ih_b, W_hh_b, b_ih_b, b_hh_b, row, half);

    if (lane < HH) partial[(size_t)wid * HH + lane] = hsum;
}

__global__ void finalize_kernel(const float* __restrict__ partial,
                                const float* __restrict__ conv_w,
                                const float* __restrict__ conv_b,
                                float* __restrict__ out) {
    int b = blockIdx.x * blockDim.x + threadIdx.x;
    if (b >= BATCH) return;
    const float* pf = partial + (size_t)(b * 2 + 0) * HH;
    const float* pb = partial + (size_t)(b * 2 + 1) * HH;
    const float inv = 1.0f / (float)TT;
#pragma unroll
    for (int o = 0; o < 2; ++o) {
        float s = 0.0f;
#pragma unroll
        for (int i = 0; i < HH; ++i) s += conv_w[o * 2 * HH + i] * pf[i];
#pragma unroll
        for (int i = 0; i < HH; ++i) s += conv_w[o * 2 * HH + HH + i] * pb[i];
        out[b * 2 + o] = fmaf(s, inv, conv_b[o]);
    }
}

extern "C" void kernel_launch(void* const* d_in, const int* in_sizes, int n_in,
                              void* d_out, int out_size, void* d_ws, size_t ws_size,
                              hipStream_t stream) {
    const float* x      = (const float*)d_in[0];
    const float* W_ih_f = (const float*)d_in[1];
    const float* W_hh_f = (const float*)d_in[2];
    const float* b_ih_f = (const float*)d_in[3];
    const float* b_hh_f = (const float*)d_in[4];
    const float* W_ih_b = (const float*)d_in[5];
    const float* W_hh_b = (const float*)d_in[6];
    const float* b_ih_b = (const float*)d_in[7];
    const float* b_hh_b = (const float*)d_in[8];
    const float* conv_w = (const float*)d_in[9];
    const float* conv_b = (const float*)d_in[10];

    float* partial = (float*)d_ws;  // 1024 * 17 floats = 68 KB
    float* out = (float*)d_out;

    rnn_kernel<<<dim3(BATCH * 2), dim3(64), 0, stream>>>(
        x, W_ih_f, W_hh_f, b_ih_f, b_hh_f, W_ih_b, W_hh_b, b_ih_b, b_hh_b, partial);
    finalize_kernel<<<dim3((BATCH + 255) / 256), dim3(256), 0, stream>>>(
        partial, conv_w, conv_b, out);
}